// Round 2
// baseline (1177.131 us; speedup 1.0000x reference)
//
#include <hip/hip_runtime.h>
#include <hip/hip_bf16.h>

#define D_DIM 256
#define MARGIN 0.25f

typedef __attribute__((ext_vector_type(8))) short short8v;   // 8 x bf16 fragment
typedef __attribute__((ext_vector_type(4))) float floatx4;   // MFMA accumulator

// ---------------- ws layout ----------------
// EHI_OFF = 0        : emb_hi  (K*256 bf16 = 512KB)
// ELO_OFF = 512K     : emb_lo  (512KB)
// ESQ_OFF = 1M       : esq     (K floats)
// CNT_OFF = 1M+4K    : counts  (K floats)
// LOSS_OFF= 1M+8K    : lossAcc (float)
// FLC_OFF = 1M+8K+64 : flagCount (int)
// FLG_OFF = 1M+16K   : flags   (N ints = 512KB)
// IDX_OFF = 1M+16K+512K : idx  (N ints = 512KB)

static __device__ __forceinline__ unsigned short f32_to_bf16(float x) {
    unsigned u = __float_as_uint(x);
    unsigned r = (u + 0x7FFFu + ((u >> 16) & 1u)) >> 16;   // RNE
    return (unsigned short)r;
}
static __device__ __forceinline__ float bf16_to_f32(unsigned short h) {
    return __uint_as_float(((unsigned)h) << 16);
}

// Split emb into bf16 hi/lo and compute exact fp32 ||e||^2.
__global__ __launch_bounds__(64) void prep_kernel(const float* __restrict__ emb,
                                                  unsigned short* __restrict__ ehi,
                                                  unsigned short* __restrict__ elo,
                                                  float* __restrict__ esq) {
    int k = blockIdx.x;
    int lane = threadIdx.x;
    float4 v = reinterpret_cast<const float4*>(emb + (size_t)k * D_DIM)[lane];
    float vv[4] = {v.x, v.y, v.z, v.w};
    unsigned short h[4], l[4];
    float s = 0.f;
    #pragma unroll
    for (int r = 0; r < 4; ++r) {
        h[r] = f32_to_bf16(vv[r]);
        l[r] = f32_to_bf16(vv[r] - bf16_to_f32(h[r]));
        s = fmaf(vv[r], vv[r], s);
    }
    size_t off = (size_t)k * D_DIM + lane * 4;
    *reinterpret_cast<uint2*>(ehi + off) =
        make_uint2((unsigned)h[0] | ((unsigned)h[1] << 16), (unsigned)h[2] | ((unsigned)h[3] << 16));
    *reinterpret_cast<uint2*>(elo + off) =
        make_uint2((unsigned)l[0] | ((unsigned)l[1] << 16), (unsigned)l[2] | ((unsigned)l[3] << 16));
    #pragma unroll
    for (int offr = 32; offr; offr >>= 1) s += __shfl_down(s, offr, 64);
    if (lane == 0) esq[k] = s;
}

// MFMA score + argmin. 4 waves/block, each wave owns 32 rows (2 M-tiles of 16),
// streams codes in chunks of 32 (2 N-tiles). A (z) held in regs for whole K loop.
// No LDS, no barriers. Tracks (min1, min2, idx); close calls get flagged for rescore.
__global__ __launch_bounds__(256, 2) void argmin_mfma_kernel(
    const float* __restrict__ z, const unsigned short* __restrict__ ehi,
    const unsigned short* __restrict__ elo, const float* __restrict__ esq,
    int* __restrict__ out_idx, int* __restrict__ flags, int* __restrict__ flagCount,
    int K)
{
    const int tid = threadIdx.x;
    const int lane = tid & 63;
    const int wid = tid >> 6;
    const int l15 = lane & 15;
    const int lk8 = (lane >> 4) << 3;   // k-offset within 32-chunk: 0,8,16,24
    const int rowbase = blockIdx.x * 128 + wid * 32;

    // ---- load z rows, split to bf16 hi/lo fragments (held whole kernel) ----
    short8v ahi[2][8], alo[2][8];
    #pragma unroll
    for (int mi = 0; mi < 2; ++mi) {
        const float* zr = z + (size_t)(rowbase + mi * 16 + l15) * D_DIM + lk8;
        #pragma unroll
        for (int ks = 0; ks < 8; ++ks) {
            float4 v0 = *reinterpret_cast<const float4*>(zr + ks * 32);
            float4 v1 = *reinterpret_cast<const float4*>(zr + ks * 32 + 4);
            float vv[8] = {v0.x, v0.y, v0.z, v0.w, v1.x, v1.y, v1.z, v1.w};
            short8v h, lo;
            #pragma unroll
            for (int r = 0; r < 8; ++r) {
                unsigned short hb = f32_to_bf16(vv[r]);
                h[r] = (short)hb;
                lo[r] = (short)f32_to_bf16(vv[r] - bf16_to_f32(hb));
            }
            ahi[mi][ks] = h;
            alo[mi][ks] = lo;
        }
    }

    float best1[2][4], best2[2][4];
    int bidx[2][4];
    #pragma unroll
    for (int mi = 0; mi < 2; ++mi)
        #pragma unroll
        for (int r = 0; r < 4; ++r) { best1[mi][r] = 3.0e38f; best2[mi][r] = 3.0e38f; bidx[mi][r] = 0; }

    const size_t bl = (size_t)l15 * D_DIM + lk8;   // per-lane base into emb hi/lo

    for (int c0 = 0; c0 < K; c0 += 32) {
        floatx4 acc[2][2];
        #pragma unroll
        for (int mi = 0; mi < 2; ++mi)
            #pragma unroll
            for (int ni = 0; ni < 2; ++ni) acc[mi][ni] = (floatx4){0.f, 0.f, 0.f, 0.f};

        #pragma unroll
        for (int ks = 0; ks < 8; ++ks) {
            const size_t o0 = bl + (size_t)c0 * D_DIM + ks * 32;
            const size_t o1 = o0 + (size_t)16 * D_DIM;
            short8v bh0 = *reinterpret_cast<const short8v*>(ehi + o0);
            short8v bh1 = *reinterpret_cast<const short8v*>(ehi + o1);
            short8v bl0 = *reinterpret_cast<const short8v*>(elo + o0);
            short8v bl1 = *reinterpret_cast<const short8v*>(elo + o1);
            #pragma unroll
            for (int mi = 0; mi < 2; ++mi) {
                acc[mi][0] = __builtin_amdgcn_mfma_f32_16x16x32_bf16(ahi[mi][ks], bh0, acc[mi][0], 0, 0, 0);
                acc[mi][1] = __builtin_amdgcn_mfma_f32_16x16x32_bf16(ahi[mi][ks], bh1, acc[mi][1], 0, 0, 0);
                acc[mi][0] = __builtin_amdgcn_mfma_f32_16x16x32_bf16(alo[mi][ks], bh0, acc[mi][0], 0, 0, 0);
                acc[mi][1] = __builtin_amdgcn_mfma_f32_16x16x32_bf16(alo[mi][ks], bh1, acc[mi][1], 0, 0, 0);
                acc[mi][0] = __builtin_amdgcn_mfma_f32_16x16x32_bf16(ahi[mi][ks], bl0, acc[mi][0], 0, 0, 0);
                acc[mi][1] = __builtin_amdgcn_mfma_f32_16x16x32_bf16(ahi[mi][ks], bl1, acc[mi][1], 0, 0, 0);
            }
        }

        // scores + running (min1,min2) — per-lane codes ascending, strict < keeps first idx
        float e0 = esq[c0 + l15];
        float e1 = esq[c0 + 16 + l15];
        #pragma unroll
        for (int mi = 0; mi < 2; ++mi) {
            #pragma unroll
            for (int r = 0; r < 4; ++r) {
                float s0 = fmaf(-2.f, acc[mi][0][r], e0);
                if (s0 < best1[mi][r]) { best2[mi][r] = best1[mi][r]; best1[mi][r] = s0; bidx[mi][r] = c0 + l15; }
                else best2[mi][r] = fminf(best2[mi][r], s0);
                float s1 = fmaf(-2.f, acc[mi][1][r], e1);
                if (s1 < best1[mi][r]) { best2[mi][r] = best1[mi][r]; best1[mi][r] = s1; bidx[mi][r] = c0 + 16 + l15; }
                else best2[mi][r] = fminf(best2[mi][r], s1);
            }
        }
    }

    // reduce across the 16 lanes of each row-group (codes live on l&15)
    #pragma unroll
    for (int mi = 0; mi < 2; ++mi) {
        #pragma unroll
        for (int r = 0; r < 4; ++r) {
            float a = best1[mi][r], b = best2[mi][r];
            int i = bidx[mi][r];
            #pragma unroll
            for (int off = 8; off; off >>= 1) {
                float oa = __shfl_xor(a, off, 16);
                float ob = __shfl_xor(b, off, 16);
                int oi = __shfl_xor(i, off, 16);
                float m2 = fminf(fmaxf(a, oa), fminf(b, ob));
                if (oa < a || (oa == a && oi < i)) { a = oa; i = oi; }
                b = m2;
            }
            if (l15 == 0) {
                int row = rowbase + mi * 16 + (lane >> 4) * 4 + r;
                out_idx[row] = i;
                if (b - a < MARGIN) {
                    int p = atomicAdd(flagCount, 1);
                    flags[p] = row;
                }
            }
        }
    }
}

// Exact fp64 rescore of flagged rows against all K codes. One block per flagged row.
__global__ __launch_bounds__(256) void rescore_kernel(
    const float* __restrict__ z, const float* __restrict__ emb,
    const int* __restrict__ flags, const int* __restrict__ flagCount,
    int* __restrict__ idx, int K)
{
    __shared__ float zs[D_DIM];
    __shared__ double rvd[256];
    __shared__ int ri[256];
    const int tid = threadIdx.x;
    const int cnt = *flagCount;
    for (int fi = blockIdx.x; fi < cnt; fi += gridDim.x) {
        int row = flags[fi];
        __syncthreads();
        zs[tid] = z[(size_t)row * D_DIM + tid];
        __syncthreads();
        double bv = 1e300;
        int bi = 0;
        #pragma unroll
        for (int j = 0; j < 4; ++j) {
            int c = tid * 4 + j;
            const float* er = emb + (size_t)c * D_DIM;
            double s = 0.0;
            for (int d = 0; d < D_DIM; d += 4) {
                float4 ev = *reinterpret_cast<const float4*>(er + d);
                double d0 = (double)zs[d] - (double)ev.x;
                double d1 = (double)zs[d + 1] - (double)ev.y;
                double d2 = (double)zs[d + 2] - (double)ev.z;
                double d3 = (double)zs[d + 3] - (double)ev.w;
                s += d0 * d0 + d1 * d1 + d2 * d2 + d3 * d3;
            }
            if (s < bv) { bv = s; bi = c; }
        }
        rvd[tid] = bv; ri[tid] = bi;
        __syncthreads();
        for (int s2 = 128; s2; s2 >>= 1) {
            if (tid < s2) {
                if (rvd[tid + s2] < rvd[tid] || (rvd[tid + s2] == rvd[tid] && ri[tid + s2] < ri[tid])) {
                    rvd[tid] = rvd[tid + s2]; ri[tid] = ri[tid + s2];
                }
            }
            __syncthreads();
        }
        if (tid == 0) idx[row] = ri[0];
        __syncthreads();
    }
}

// One wave per row: gather codeword, straight-through output, loss + counts.
__global__ __launch_bounds__(256) void gather_kernel(
    const float* __restrict__ z, const float* __restrict__ emb,
    const int* __restrict__ idx, float* __restrict__ q,
    float* __restrict__ counts, float* __restrict__ lossAcc, int N) {
    const int lane = threadIdx.x & 63;
    const int wave = threadIdx.x >> 6;
    const int wavesPerBlock = blockDim.x >> 6;
    const int gw = blockIdx.x * wavesPerBlock + wave;
    const int nw = gridDim.x * wavesPerBlock;
    float ls = 0.f;
    for (int n = gw; n < N; n += nw) {
        int k = idx[n];
        float4 zv = *reinterpret_cast<const float4*>(z + (size_t)n * D_DIM + lane * 4);
        float4 ev = *reinterpret_cast<const float4*>(emb + (size_t)k * D_DIM + lane * 4);
        float4 df, o;
        df.x = ev.x - zv.x; df.y = ev.y - zv.y; df.z = ev.z - zv.z; df.w = ev.w - zv.w;
        o.x = zv.x + df.x; o.y = zv.y + df.y; o.z = zv.z + df.z; o.w = zv.w + df.w;
        *reinterpret_cast<float4*>(q + (size_t)n * D_DIM + lane * 4) = o;
        ls = fmaf(df.x, df.x, ls); ls = fmaf(df.y, df.y, ls);
        ls = fmaf(df.z, df.z, ls); ls = fmaf(df.w, df.w, ls);
        if (lane == 0) atomicAdd(&counts[k], 1.0f);
    }
    #pragma unroll
    for (int off = 32; off; off >>= 1) ls += __shfl_down(ls, off, 64);
    __shared__ float red[8];
    if (lane == 0) red[wave] = ls;
    __syncthreads();
    if (threadIdx.x == 0) {
        float t = 0.f;
        for (int w = 0; w < wavesPerBlock; ++w) t += red[w];
        atomicAdd(lossAcc, t);
    }
}

__global__ __launch_bounds__(256) void finalize_kernel(
    const float* __restrict__ counts, const float* __restrict__ lossAcc,
    float* __restrict__ out_loss, float* __restrict__ out_perp,
    int K, float invN, float invND) {
    __shared__ float red[256];
    int t = threadIdx.x;
    float h = 0.f;
    for (int k = t; k < K; k += 256) {
        float p = counts[k] * invN;
        h += p * logf(p + 1e-10f);
    }
    red[t] = h;
    __syncthreads();
    for (int s = 128; s; s >>= 1) {
        if (t < s) red[t] += red[t + s];
        __syncthreads();
    }
    if (t == 0) {
        out_loss[0] = 0.25f * lossAcc[0] * invND;
        out_perp[0] = expf(-red[0]);
    }
}

extern "C" void kernel_launch(void* const* d_in, const int* in_sizes, int n_in,
                              void* d_out, int out_size, void* d_ws, size_t ws_size,
                              hipStream_t stream) {
    const float* z = (const float*)d_in[0];
    const float* emb = (const float*)d_in[1];
    const int N = in_sizes[0] / D_DIM;   // 131072
    const int K = in_sizes[1] / D_DIM;   // 1024
    float* out = (float*)d_out;

    char* ws = (char*)d_ws;
    const size_t EHI_OFF = 0;
    const size_t ELO_OFF = 512 * 1024;
    const size_t ESQ_OFF = 1024 * 1024;
    const size_t CNT_OFF = ESQ_OFF + 4096;
    const size_t LOSS_OFF = CNT_OFF + 4096;
    const size_t FLC_OFF = LOSS_OFF + 64;
    const size_t FLG_OFF = ESQ_OFF + 16384;
    const size_t IDX_OFF = FLG_OFF + 512 * 1024;

    unsigned short* ehi = (unsigned short*)(ws + EHI_OFF);
    unsigned short* elo = (unsigned short*)(ws + ELO_OFF);
    float* esq = (float*)(ws + ESQ_OFF);
    float* counts = (float*)(ws + CNT_OFF);
    float* lossAcc = (float*)(ws + LOSS_OFF);
    int* flagCount = (int*)(ws + FLC_OFF);
    int* flags = (int*)(ws + FLG_OFF);
    int* idx = (int*)(ws + IDX_OFF);

    // zero counts + lossAcc + flagCount (ws is poisoned before every launch)
    hipMemsetAsync(ws + CNT_OFF, 0, 4096 + 128, stream);

    prep_kernel<<<K, 64, 0, stream>>>(emb, ehi, elo, esq);
    argmin_mfma_kernel<<<N / 128, 256, 0, stream>>>(z, ehi, elo, esq, idx, flags, flagCount, K);
    rescore_kernel<<<1024, 256, 0, stream>>>(z, emb, flags, flagCount, idx, K);
    gather_kernel<<<2048, 256, 0, stream>>>(z, emb, idx, out + 1, counts, lossAcc, N);
    finalize_kernel<<<1, 256, 0, stream>>>(counts, lossAcc, out,
                                           out + 1 + (size_t)N * D_DIM, K,
                                           1.0f / (float)N, 1.0f / ((float)N * (float)D_DIM));
}

// Round 3
// 726.333 us; speedup vs baseline: 1.6206x; 1.6206x over previous
//
#include <hip/hip_runtime.h>
#include <hip/hip_bf16.h>

#define D_DIM 256
#define MARGIN 0.12f

typedef __attribute__((ext_vector_type(8))) _Float16 half8v;   // 8 x f16 fragment (4 VGPR)
typedef __attribute__((ext_vector_type(4))) _Float16 half4v;
typedef __attribute__((ext_vector_type(4))) float floatx4;     // MFMA accumulator

// ---------------- ws layout ----------------
// EHF_OFF = 0          : emb_f16 (K*256 f16 = 512KB)
// ESQ_OFF = 512K       : esq     (K floats)
// CNT_OFF = 512K+4K    : counts  (K floats)
// LOSS_OFF= 512K+8K    : lossAcc (float)
// FLC_OFF = 512K+8K+64 : flagCount (int)
// FLG_OFF = 512K+16K   : flags   (N ints = 512KB)
// IDX_OFF = 512K+16K+512K : idx  (N ints = 512KB)

// emb -> f16 + exact fp32 ||e||^2
__global__ __launch_bounds__(64) void prep_kernel(const float* __restrict__ emb,
                                                  _Float16* __restrict__ ehf,
                                                  float* __restrict__ esq) {
    int k = blockIdx.x;
    int lane = threadIdx.x;
    float4 v = reinterpret_cast<const float4*>(emb + (size_t)k * D_DIM)[lane];
    half4v h;
    h[0] = (_Float16)v.x; h[1] = (_Float16)v.y; h[2] = (_Float16)v.z; h[3] = (_Float16)v.w;
    *reinterpret_cast<half4v*>(ehf + (size_t)k * D_DIM + lane * 4) = h;
    float s = fmaf(v.x, v.x, fmaf(v.y, v.y, fmaf(v.z, v.z, v.w * v.w)));
    #pragma unroll
    for (int off = 32; off; off >>= 1) s += __shfl_down(s, off, 64);
    if (lane == 0) esq[k] = s;
}

// f16-MFMA score + argmin. 4 waves/block, wave owns 32 rows (2 M-tiles of 16),
// streams codes in chunks of 32 (2 N-tiles), 1 MFMA per acc per ks (4 indep chains).
// Per-chunk barrier keeps waves lockstepped so identical B loads share L1.
__global__ __launch_bounds__(256, 4) void argmin_f16_kernel(
    const float* __restrict__ z, const _Float16* __restrict__ ehf,
    const float* __restrict__ esq, int* __restrict__ out_idx,
    int* __restrict__ flags, int* __restrict__ flagCount, int K)
{
    const int tid = threadIdx.x;
    const int lane = tid & 63;
    const int wid = tid >> 6;
    const int l15 = lane & 15;
    const int lk8 = (lane >> 4) << 3;   // k-offset within 32-chunk: 0,8,16,24
    const int rowbase = blockIdx.x * 128 + wid * 32;

    // ---- load z rows, convert to f16 fragments (held whole kernel: 64 VGPR) ----
    half8v a[2][8];
    #pragma unroll
    for (int mi = 0; mi < 2; ++mi) {
        const float* zr = z + (size_t)(rowbase + mi * 16 + l15) * D_DIM + lk8;
        #pragma unroll
        for (int ks = 0; ks < 8; ++ks) {
            float4 v0 = *reinterpret_cast<const float4*>(zr + ks * 32);
            float4 v1 = *reinterpret_cast<const float4*>(zr + ks * 32 + 4);
            half8v h;
            h[0] = (_Float16)v0.x; h[1] = (_Float16)v0.y;
            h[2] = (_Float16)v0.z; h[3] = (_Float16)v0.w;
            h[4] = (_Float16)v1.x; h[5] = (_Float16)v1.y;
            h[6] = (_Float16)v1.z; h[7] = (_Float16)v1.w;
            a[mi][ks] = h;
        }
    }

    float best1[2][4], best2[2][4];
    int bidx[2][4];
    #pragma unroll
    for (int mi = 0; mi < 2; ++mi)
        #pragma unroll
        for (int r = 0; r < 4; ++r) { best1[mi][r] = 3.0e38f; best2[mi][r] = 3.0e38f; bidx[mi][r] = 0; }

    const size_t bl = (size_t)l15 * D_DIM + lk8;   // per-lane base into ehf

    for (int c0 = 0; c0 < K; c0 += 32) {
        __syncthreads();   // keep the 4 waves together -> B loads hit L1
        floatx4 acc[2][2];
        #pragma unroll
        for (int mi = 0; mi < 2; ++mi)
            #pragma unroll
            for (int ni = 0; ni < 2; ++ni) acc[mi][ni] = (floatx4){0.f, 0.f, 0.f, 0.f};

        #pragma unroll
        for (int ks = 0; ks < 8; ++ks) {
            const size_t o0 = bl + (size_t)c0 * D_DIM + ks * 32;
            half8v b0 = *reinterpret_cast<const half8v*>(ehf + o0);
            half8v b1 = *reinterpret_cast<const half8v*>(ehf + o0 + (size_t)16 * D_DIM);
            acc[0][0] = __builtin_amdgcn_mfma_f32_16x16x32_f16(a[0][ks], b0, acc[0][0], 0, 0, 0);
            acc[0][1] = __builtin_amdgcn_mfma_f32_16x16x32_f16(a[0][ks], b1, acc[0][1], 0, 0, 0);
            acc[1][0] = __builtin_amdgcn_mfma_f32_16x16x32_f16(a[1][ks], b0, acc[1][0], 0, 0, 0);
            acc[1][1] = __builtin_amdgcn_mfma_f32_16x16x32_f16(a[1][ks], b1, acc[1][1], 0, 0, 0);
        }

        // scores + running (min1,min2); per-lane codes ascending, strict < keeps first idx
        float e0 = esq[c0 + l15];
        float e1 = esq[c0 + 16 + l15];
        #pragma unroll
        for (int mi = 0; mi < 2; ++mi) {
            #pragma unroll
            for (int r = 0; r < 4; ++r) {
                float s0 = fmaf(-2.f, acc[mi][0][r], e0);
                if (s0 < best1[mi][r]) { best2[mi][r] = best1[mi][r]; best1[mi][r] = s0; bidx[mi][r] = c0 + l15; }
                else best2[mi][r] = fminf(best2[mi][r], s0);
                float s1 = fmaf(-2.f, acc[mi][1][r], e1);
                if (s1 < best1[mi][r]) { best2[mi][r] = best1[mi][r]; best1[mi][r] = s1; bidx[mi][r] = c0 + 16 + l15; }
                else best2[mi][r] = fminf(best2[mi][r], s1);
            }
        }
    }

    // reduce across the 16 lanes of each row-group (codes live on l&15)
    #pragma unroll
    for (int mi = 0; mi < 2; ++mi) {
        #pragma unroll
        for (int r = 0; r < 4; ++r) {
            float a1 = best1[mi][r], b2 = best2[mi][r];
            int i = bidx[mi][r];
            #pragma unroll
            for (int off = 8; off; off >>= 1) {
                float oa = __shfl_xor(a1, off, 16);
                float ob = __shfl_xor(b2, off, 16);
                int oi = __shfl_xor(i, off, 16);
                float m2 = fminf(fmaxf(a1, oa), fminf(b2, ob));
                if (oa < a1 || (oa == a1 && oi < i)) { a1 = oa; i = oi; }
                b2 = m2;
            }
            if (l15 == 0) {
                int row = rowbase + mi * 16 + (lane >> 4) * 4 + r;
                out_idx[row] = i;
                if (b2 - a1 < MARGIN) {
                    int p = atomicAdd(flagCount, 1);
                    flags[p] = row;
                }
            }
        }
    }
}

// Exact fp32 rescore (reference-matching arithmetic: esq - 2*dot, fmaf chain).
__global__ __launch_bounds__(256) void rescore_kernel(
    const float* __restrict__ z, const float* __restrict__ emb,
    const float* __restrict__ esq,
    const int* __restrict__ flags, const int* __restrict__ flagCount,
    int* __restrict__ idx, int K)
{
    __shared__ float zs[D_DIM];
    __shared__ float rv[256];
    __shared__ int ri[256];
    const int tid = threadIdx.x;
    const int cnt = *flagCount;
    for (int fi = blockIdx.x; fi < cnt; fi += gridDim.x) {
        int row = flags[fi];
        __syncthreads();
        zs[tid] = z[(size_t)row * D_DIM + tid];
        __syncthreads();
        float bv = 3.0e38f;
        int bi = 0;
        #pragma unroll
        for (int j = 0; j < 4; ++j) {
            int c = tid * 4 + j;
            const float* er = emb + (size_t)c * D_DIM;
            float dot = 0.f;
            for (int d = 0; d < D_DIM; d += 4) {
                float4 ev = *reinterpret_cast<const float4*>(er + d);
                dot = fmaf(zs[d], ev.x, dot);
                dot = fmaf(zs[d + 1], ev.y, dot);
                dot = fmaf(zs[d + 2], ev.z, dot);
                dot = fmaf(zs[d + 3], ev.w, dot);
            }
            float s = fmaf(-2.f, dot, esq[c]);
            if (s < bv) { bv = s; bi = c; }
        }
        rv[tid] = bv; ri[tid] = bi;
        __syncthreads();
        for (int s2 = 128; s2; s2 >>= 1) {
            if (tid < s2) {
                if (rv[tid + s2] < rv[tid] || (rv[tid + s2] == rv[tid] && ri[tid + s2] < ri[tid])) {
                    rv[tid] = rv[tid + s2]; ri[tid] = ri[tid + s2];
                }
            }
            __syncthreads();
        }
        if (tid == 0) idx[row] = ri[0];
        __syncthreads();
    }
}

// One wave per row: gather codeword, straight-through output, loss + counts.
__global__ __launch_bounds__(256) void gather_kernel(
    const float* __restrict__ z, const float* __restrict__ emb,
    const int* __restrict__ idx, float* __restrict__ q,
    float* __restrict__ counts, float* __restrict__ lossAcc, int N) {
    const int lane = threadIdx.x & 63;
    const int wave = threadIdx.x >> 6;
    const int wavesPerBlock = blockDim.x >> 6;
    const int gw = blockIdx.x * wavesPerBlock + wave;
    const int nw = gridDim.x * wavesPerBlock;
    float ls = 0.f;
    for (int n = gw; n < N; n += nw) {
        int k = idx[n];
        float4 zv = *reinterpret_cast<const float4*>(z + (size_t)n * D_DIM + lane * 4);
        float4 ev = *reinterpret_cast<const float4*>(emb + (size_t)k * D_DIM + lane * 4);
        float4 df, o;
        df.x = ev.x - zv.x; df.y = ev.y - zv.y; df.z = ev.z - zv.z; df.w = ev.w - zv.w;
        o.x = zv.x + df.x; o.y = zv.y + df.y; o.z = zv.z + df.z; o.w = zv.w + df.w;
        *reinterpret_cast<float4*>(q + (size_t)n * D_DIM + lane * 4) = o;
        ls = fmaf(df.x, df.x, ls); ls = fmaf(df.y, df.y, ls);
        ls = fmaf(df.z, df.z, ls); ls = fmaf(df.w, df.w, ls);
        if (lane == 0) atomicAdd(&counts[k], 1.0f);
    }
    #pragma unroll
    for (int off = 32; off; off >>= 1) ls += __shfl_down(ls, off, 64);
    __shared__ float red[8];
    if (lane == 0) red[wave] = ls;
    __syncthreads();
    if (threadIdx.x == 0) {
        float t = 0.f;
        for (int w = 0; w < wavesPerBlock; ++w) t += red[w];
        atomicAdd(lossAcc, t);
    }
}

__global__ __launch_bounds__(256) void finalize_kernel(
    const float* __restrict__ counts, const float* __restrict__ lossAcc,
    float* __restrict__ out_loss, float* __restrict__ out_perp,
    int K, float invN, float invND) {
    __shared__ float red[256];
    int t = threadIdx.x;
    float h = 0.f;
    for (int k = t; k < K; k += 256) {
        float p = counts[k] * invN;
        h += p * logf(p + 1e-10f);
    }
    red[t] = h;
    __syncthreads();
    for (int s = 128; s; s >>= 1) {
        if (t < s) red[t] += red[t + s];
        __syncthreads();
    }
    if (t == 0) {
        out_loss[0] = 0.25f * lossAcc[0] * invND;
        out_perp[0] = expf(-red[0]);
    }
}

extern "C" void kernel_launch(void* const* d_in, const int* in_sizes, int n_in,
                              void* d_out, int out_size, void* d_ws, size_t ws_size,
                              hipStream_t stream) {
    const float* z = (const float*)d_in[0];
    const float* emb = (const float*)d_in[1];
    const int N = in_sizes[0] / D_DIM;   // 131072
    const int K = in_sizes[1] / D_DIM;   // 1024
    float* out = (float*)d_out;

    char* ws = (char*)d_ws;
    const size_t EHF_OFF = 0;
    const size_t ESQ_OFF = 512 * 1024;
    const size_t CNT_OFF = ESQ_OFF + 4096;
    const size_t LOSS_OFF = CNT_OFF + 4096;
    const size_t FLC_OFF = LOSS_OFF + 64;
    const size_t FLG_OFF = ESQ_OFF + 16384;
    const size_t IDX_OFF = FLG_OFF + 512 * 1024;

    _Float16* ehf = (_Float16*)(ws + EHF_OFF);
    float* esq = (float*)(ws + ESQ_OFF);
    float* counts = (float*)(ws + CNT_OFF);
    float* lossAcc = (float*)(ws + LOSS_OFF);
    int* flagCount = (int*)(ws + FLC_OFF);
    int* flags = (int*)(ws + FLG_OFF);
    int* idx = (int*)(ws + IDX_OFF);

    // zero counts + lossAcc + flagCount (ws is poisoned before every launch)
    hipMemsetAsync(ws + CNT_OFF, 0, 4096 + 128, stream);

    prep_kernel<<<K, 64, 0, stream>>>(emb, ehf, esq);
    argmin_f16_kernel<<<N / 128, 256, 0, stream>>>(z, ehf, esq, idx, flags, flagCount, K);
    rescore_kernel<<<1024, 256, 0, stream>>>(z, emb, esq, flags, flagCount, idx, K);
    gather_kernel<<<2048, 256, 0, stream>>>(z, emb, idx, out + 1, counts, lossAcc, N);
    finalize_kernel<<<1, 256, 0, stream>>>(counts, lossAcc, out,
                                           out + 1 + (size_t)N * D_DIM, K,
                                           1.0f / (float)N, 1.0f / ((float)N * (float)D_DIM));
}

// Round 4
// 565.790 us; speedup vs baseline: 2.0805x; 1.2838x over previous
//
#include <hip/hip_runtime.h>
#include <hip/hip_bf16.h>

#define D_DIM 256
#define MARGIN 0.12f

typedef __attribute__((ext_vector_type(8))) _Float16 half8v;   // 8 x f16 fragment (4 VGPR)
typedef __attribute__((ext_vector_type(4))) _Float16 half4v;
typedef __attribute__((ext_vector_type(4))) float floatx4;     // MFMA accumulator

// ---------------- ws layout ----------------
// EHF_OFF = 0          : emb_f16 (K*256 f16 = 512KB)
// ESQ_OFF = 512K       : esq     (K floats)
// CNT_OFF = 512K+4K    : counts  (K floats)
// LOSS_OFF= 512K+8K    : lossAcc (float)
// FLC_OFF = 512K+8K+64 : flagCount (int)
// FLG_OFF = 512K+16K   : flags   (N ints = 512KB)

// emb -> f16 + exact fp32 ||e||^2
__global__ __launch_bounds__(64) void prep_kernel(const float* __restrict__ emb,
                                                  _Float16* __restrict__ ehf,
                                                  float* __restrict__ esq) {
    int k = blockIdx.x;
    int lane = threadIdx.x;
    float4 v = reinterpret_cast<const float4*>(emb + (size_t)k * D_DIM)[lane];
    half4v h;
    h[0] = (_Float16)v.x; h[1] = (_Float16)v.y; h[2] = (_Float16)v.z; h[3] = (_Float16)v.w;
    *reinterpret_cast<half4v*>(ehf + (size_t)k * D_DIM + lane * 4) = h;
    float s = fmaf(v.x, v.x, fmaf(v.y, v.y, fmaf(v.z, v.z, v.w * v.w)));
    #pragma unroll
    for (int off = 32; off; off >>= 1) s += __shfl_down(s, off, 64);
    if (lane == 0) esq[k] = s;
}

// Issue one chunk (32 codes x 256 dims f16 = 16KB) global->LDS, swizzled source.
// LDS physical slot p (16B units) of code row c holds global slot (p ^ (c&7)),
// so ds_read with the same XOR is bank-conflict-free (8 lanes per 4-bank group).
static __device__ __forceinline__ void stage_chunk(const _Float16* __restrict__ ehf,
                                                   char* lbuf, int c0, int wid, int lane) {
    #pragma unroll
    for (int i = 0; i < 2; ++i) {
        int o = wid * 2048 + i * 1024 + lane * 16;   // per-lane LDS byte offset (linear)
        int code = o >> 9;                           // 0..31
        int p = (o >> 4) & 31;                       // physical 16B slot within row
        int srcSlot = p ^ (code & 7);
        const _Float16* src = ehf + (size_t)(c0 + code) * D_DIM + srcSlot * 8;
        __builtin_amdgcn_global_load_lds(
            (const __attribute__((address_space(1))) unsigned int*)src,
            (__attribute__((address_space(3))) unsigned int*)(lbuf + wid * 2048 + i * 1024),
            16, 0, 0);
    }
}

// Fused: f16-MFMA scores + argmin + (for unflagged rows) gather/ST-output/loss/counts.
// 8 waves x 32 rows = 256 rows per block. B double-buffered in LDS (m97 2-phase).
__global__ __launch_bounds__(512, 4) void argmin_fused_kernel(
    const float* __restrict__ z, const float* __restrict__ emb,
    const _Float16* __restrict__ ehf, const float* __restrict__ esq,
    float* __restrict__ qout, float* __restrict__ counts, float* __restrict__ lossAcc,
    int* __restrict__ flags, int* __restrict__ flagCount, int K)
{
    __shared__ char bstage[2][16384];
    __shared__ float esql[1024];

    const int tid = threadIdx.x;
    const int lane = tid & 63;
    const int wid = tid >> 6;
    const int l15 = lane & 15;
    const int lk8 = (lane >> 4) << 3;     // k-offset within 32-chunk: 0,8,16,24
    const int rowbase = blockIdx.x * 256 + wid * 32;

    // stage chunk 0 + esq into LDS (completed by first loop barrier)
    stage_chunk(ehf, bstage[0], 0, wid, lane);
    esql[tid] = esq[tid];
    esql[tid + 512] = esq[tid + 512];

    // ---- load z rows, convert to f16 fragments (64 VGPR, held whole loop) ----
    half8v a[2][8];
    #pragma unroll
    for (int mi = 0; mi < 2; ++mi) {
        const float* zr = z + (size_t)(rowbase + mi * 16 + l15) * D_DIM + lk8;
        #pragma unroll
        for (int ks = 0; ks < 8; ++ks) {
            float4 v0 = *reinterpret_cast<const float4*>(zr + ks * 32);
            float4 v1 = *reinterpret_cast<const float4*>(zr + ks * 32 + 4);
            half8v h;
            h[0] = (_Float16)v0.x; h[1] = (_Float16)v0.y;
            h[2] = (_Float16)v0.z; h[3] = (_Float16)v0.w;
            h[4] = (_Float16)v1.x; h[5] = (_Float16)v1.y;
            h[6] = (_Float16)v1.z; h[7] = (_Float16)v1.w;
            a[mi][ks] = h;
        }
    }

    float best1[2][4], best2[2][4];
    int bidx[2][4];
    #pragma unroll
    for (int mi = 0; mi < 2; ++mi)
        #pragma unroll
        for (int r = 0; r < 4; ++r) { best1[mi][r] = 3.0e38f; best2[mi][r] = 3.0e38f; bidx[mi][r] = 0; }

    const int h3 = l15 & 7;   // swizzle key (same for code c and c+16)

    const int NT = K / 32;    // 32 chunks
    for (int t = 0; t < NT; ++t) {
        __syncthreads();                     // drains vmcnt: buf[t&1] ready; prior reads of buf[(t+1)&1] done
        if (t + 1 < NT) stage_chunk(ehf, bstage[(t + 1) & 1], (t + 1) * 32, wid, lane);

        const char* lb = bstage[t & 1];
        floatx4 acc[2][2];
        #pragma unroll
        for (int mi = 0; mi < 2; ++mi)
            #pragma unroll
            for (int ni = 0; ni < 2; ++ni) acc[mi][ni] = (floatx4){0.f, 0.f, 0.f, 0.f};

        #pragma unroll
        for (int ks = 0; ks < 8; ++ks) {
            int slot = (lane >> 4) + 4 * ks;
            int po = (slot ^ h3) << 4;
            half8v b0 = *reinterpret_cast<const half8v*>(lb + l15 * 512 + po);
            half8v b1 = *reinterpret_cast<const half8v*>(lb + (l15 + 16) * 512 + po);
            acc[0][0] = __builtin_amdgcn_mfma_f32_16x16x32_f16(a[0][ks], b0, acc[0][0], 0, 0, 0);
            acc[0][1] = __builtin_amdgcn_mfma_f32_16x16x32_f16(a[0][ks], b1, acc[0][1], 0, 0, 0);
            acc[1][0] = __builtin_amdgcn_mfma_f32_16x16x32_f16(a[1][ks], b0, acc[1][0], 0, 0, 0);
            acc[1][1] = __builtin_amdgcn_mfma_f32_16x16x32_f16(a[1][ks], b1, acc[1][1], 0, 0, 0);
        }

        int c0 = t * 32;
        float e0 = esql[c0 + l15];
        float e1 = esql[c0 + 16 + l15];
        #pragma unroll
        for (int mi = 0; mi < 2; ++mi) {
            #pragma unroll
            for (int r = 0; r < 4; ++r) {
                float s0 = fmaf(-2.f, acc[mi][0][r], e0);
                if (s0 < best1[mi][r]) { best2[mi][r] = best1[mi][r]; best1[mi][r] = s0; bidx[mi][r] = c0 + l15; }
                else best2[mi][r] = fminf(best2[mi][r], s0);
                float s1 = fmaf(-2.f, acc[mi][1][r], e1);
                if (s1 < best1[mi][r]) { best2[mi][r] = best1[mi][r]; best1[mi][r] = s1; bidx[mi][r] = c0 + 16 + l15; }
                else best2[mi][r] = fminf(best2[mi][r], s1);
            }
        }
    }

    // 16-lane symmetric butterfly: afterwards ALL lanes hold the final (min1,min2,idx)
    // for rows rowbase + mi*16 + (lane>>4)*4 + r.
    int packed[2][4];
    #pragma unroll
    for (int mi = 0; mi < 2; ++mi) {
        #pragma unroll
        for (int r = 0; r < 4; ++r) {
            float a1 = best1[mi][r], b2 = best2[mi][r];
            int i = bidx[mi][r];
            #pragma unroll
            for (int off = 8; off; off >>= 1) {
                float oa = __shfl_xor(a1, off, 16);
                float ob = __shfl_xor(b2, off, 16);
                int oi = __shfl_xor(i, off, 16);
                float m2 = fminf(fmaxf(a1, oa), fminf(b2, ob));
                if (oa < a1 || (oa == a1 && oi < i)) { a1 = oa; i = oi; }
                b2 = m2;
            }
            bool flg = (b2 - a1 < MARGIN);
            packed[mi][r] = i | (flg ? (int)0x80000000 : 0);
            if (l15 == 0 && flg) {
                int row = rowbase + mi * 16 + (lane >> 4) * 4 + r;
                int p = atomicAdd(flagCount, 1);
                flags[p] = row;
            }
        }
    }

    // Fused epilogue: unflagged rows -> gather e[k], write q = z + (e - z),
    // accumulate loss + counts. Flagged rows are fully handled by rescore_kernel.
    float ls = 0.f;
    #pragma unroll
    for (int j = 0; j < 32; ++j) {
        const int mi = j >> 4;
        const int r = j & 3;
        const int srcLane = ((j & 15) >> 2) << 4;
        int pk = __shfl(packed[mi][r], srcLane, 64);   // wave-uniform
        if (pk >= 0) {
            int k = pk;
            int row = rowbase + j;
            float4 zv = *reinterpret_cast<const float4*>(z + (size_t)row * D_DIM + lane * 4);
            float4 ev = *reinterpret_cast<const float4*>(emb + (size_t)k * D_DIM + lane * 4);
            float4 df, o;
            df.x = ev.x - zv.x; df.y = ev.y - zv.y; df.z = ev.z - zv.z; df.w = ev.w - zv.w;
            o.x = zv.x + df.x; o.y = zv.y + df.y; o.z = zv.z + df.z; o.w = zv.w + df.w;
            *reinterpret_cast<float4*>(qout + (size_t)row * D_DIM + lane * 4) = o;
            ls = fmaf(df.x, df.x, ls); ls = fmaf(df.y, df.y, ls);
            ls = fmaf(df.z, df.z, ls); ls = fmaf(df.w, df.w, ls);
            if (lane == 0) atomicAdd(&counts[k], 1.0f);
        }
    }
    #pragma unroll
    for (int off = 32; off; off >>= 1) ls += __shfl_down(ls, off, 64);
    if (lane == 0) atomicAdd(lossAcc, ls);
}

// Exact fp32 rescore (reference-matching arithmetic) + full epilogue for flagged rows.
__global__ __launch_bounds__(256) void rescore_kernel(
    const float* __restrict__ z, const float* __restrict__ emb,
    const float* __restrict__ esq,
    const int* __restrict__ flags, const int* __restrict__ flagCount,
    float* __restrict__ qout, float* __restrict__ counts, float* __restrict__ lossAcc,
    int K)
{
    __shared__ float zs[D_DIM];
    __shared__ float rv[256];
    __shared__ int ri[256];
    const int tid = threadIdx.x;
    const int cnt = *flagCount;
    for (int fi = blockIdx.x; fi < cnt; fi += gridDim.x) {
        int row = flags[fi];
        __syncthreads();
        zs[tid] = z[(size_t)row * D_DIM + tid];
        __syncthreads();
        float bv = 3.0e38f;
        int bi = 0;
        #pragma unroll
        for (int j = 0; j < 4; ++j) {
            int c = tid * 4 + j;
            const float* er = emb + (size_t)c * D_DIM;
            float dot = 0.f;
            for (int d = 0; d < D_DIM; d += 4) {
                float4 ev = *reinterpret_cast<const float4*>(er + d);
                dot = fmaf(zs[d], ev.x, dot);
                dot = fmaf(zs[d + 1], ev.y, dot);
                dot = fmaf(zs[d + 2], ev.z, dot);
                dot = fmaf(zs[d + 3], ev.w, dot);
            }
            float s = fmaf(-2.f, dot, esq[c]);
            if (s < bv) { bv = s; bi = c; }
        }
        rv[tid] = bv; ri[tid] = bi;
        __syncthreads();
        for (int s2 = 128; s2; s2 >>= 1) {
            if (tid < s2) {
                if (rv[tid + s2] < rv[tid] || (rv[tid + s2] == rv[tid] && ri[tid + s2] < ri[tid])) {
                    rv[tid] = rv[tid + s2]; ri[tid] = ri[tid + s2];
                }
            }
            __syncthreads();
        }
        int k = ri[0];
        // epilogue for this flagged row
        float zvv = zs[tid];
        float evv = emb[(size_t)k * D_DIM + tid];
        float df = evv - zvv;
        qout[(size_t)row * D_DIM + tid] = zvv + df;
        rv[tid] = df * df;
        __syncthreads();
        for (int s2 = 128; s2; s2 >>= 1) {
            if (tid < s2) rv[tid] += rv[tid + s2];
            __syncthreads();
        }
        if (tid == 0) {
            atomicAdd(lossAcc, rv[0]);
            atomicAdd(&counts[k], 1.0f);
        }
        __syncthreads();
    }
}

__global__ __launch_bounds__(256) void finalize_kernel(
    const float* __restrict__ counts, const float* __restrict__ lossAcc,
    float* __restrict__ out_loss, float* __restrict__ out_perp,
    int K, float invN, float invND) {
    __shared__ float red[256];
    int t = threadIdx.x;
    float h = 0.f;
    for (int k = t; k < K; k += 256) {
        float p = counts[k] * invN;
        h += p * logf(p + 1e-10f);
    }
    red[t] = h;
    __syncthreads();
    for (int s = 128; s; s >>= 1) {
        if (t < s) red[t] += red[t + s];
        __syncthreads();
    }
    if (t == 0) {
        out_loss[0] = 0.25f * lossAcc[0] * invND;
        out_perp[0] = expf(-red[0]);
    }
}

extern "C" void kernel_launch(void* const* d_in, const int* in_sizes, int n_in,
                              void* d_out, int out_size, void* d_ws, size_t ws_size,
                              hipStream_t stream) {
    const float* z = (const float*)d_in[0];
    const float* emb = (const float*)d_in[1];
    const int N = in_sizes[0] / D_DIM;   // 131072
    const int K = in_sizes[1] / D_DIM;   // 1024
    float* out = (float*)d_out;

    char* ws = (char*)d_ws;
    const size_t EHF_OFF = 0;
    const size_t ESQ_OFF = 512 * 1024;
    const size_t CNT_OFF = ESQ_OFF + 4096;
    const size_t LOSS_OFF = CNT_OFF + 4096;
    const size_t FLC_OFF = LOSS_OFF + 64;
    const size_t FLG_OFF = ESQ_OFF + 16384;

    _Float16* ehf = (_Float16*)(ws + EHF_OFF);
    float* esq = (float*)(ws + ESQ_OFF);
    float* counts = (float*)(ws + CNT_OFF);
    float* lossAcc = (float*)(ws + LOSS_OFF);
    int* flagCount = (int*)(ws + FLC_OFF);
    int* flags = (int*)(ws + FLG_OFF);

    // zero counts + lossAcc + flagCount (ws is re-poisoned before every launch)
    hipMemsetAsync(ws + CNT_OFF, 0, 4096 + 128, stream);

    prep_kernel<<<K, 64, 0, stream>>>(emb, ehf, esq);
    argmin_fused_kernel<<<N / 256, 512, 0, stream>>>(z, emb, ehf, esq, out + 1,
                                                     counts, lossAcc, flags, flagCount, K);
    rescore_kernel<<<2048, 256, 0, stream>>>(z, emb, esq, flags, flagCount,
                                             out + 1, counts, lossAcc, K);
    finalize_kernel<<<1, 256, 0, stream>>>(counts, lossAcc, out,
                                           out + 1 + (size_t)N * D_DIM, K,
                                           1.0f / (float)N, 1.0f / ((float)N * (float)D_DIM));
}